// Round 6
// baseline (344.942 us; speedup 1.0000x reference)
//
#include <hip/hip_runtime.h>

// Spiking NN collapses to 3 dependent masked binary matvecs (input drive is
// nonzero only at t=0; decaying membranes can never re-cross threshold):
//   enc = (u < x);  s0 = (W0*M0)@enc > 1;  s1 = (W1*M1)@s0 > 1;
//   out = ((W2*M2)@s1 > 1) ? 1/time_steps : 0
// v7: v0/v5/v6 all measured ~3.5 TB/s for the mandatory 384 MB W+M stream
// (vs 6.7-7.0 TB/s fill BW on the same chip). Common structure: burst-
// drain-die waves (one latency-deep load burst, vmcnt(0), compute, exit)
// -> read pipe idles during compute + block turnover. v7 streams
// continuously: 512 blocks = exactly 2/CU, ALL co-resident (zero
// turnover); each wave double-buffers 4KB+4KB chunks through LDS via
// global_load_lds with COUNTED vmcnt(8) waits (never 0 mid-loop), so the
// next chunk is always in flight under the current chunk's compute.
// Spike vectors travel as 512 B bitmasks (ballot in encoder; one byte per
// block per layer) so the hot loop's vmem ops are exactly the 8 DMAs/chunk.

constexpr int N = 4096;
typedef float f32x4 __attribute__((ext_vector_type(4)));

#define GLOBAL_AS __attribute__((address_space(1)))
#define LDS_AS    __attribute__((address_space(3)))

// ---------- encoder: 4096 bits of (u < x) via ballot ----------
__global__ __launch_bounds__(256) void enc_kernel(
    const float* __restrict__ x, const float* __restrict__ u,
    unsigned long long* __restrict__ emask)
{
    const int j = blockIdx.x * 256 + threadIdx.x;
    const unsigned long long b = __ballot(u[j] < x[j]);
    if ((threadIdx.x & 63) == 0) emask[j >> 6] = b;
}

// ---------- layer ----------
__device__ __forceinline__ void issue_chunk(
    const f32x4* __restrict__ Wrow, const f32x4* __restrict__ Mrow,
    int c, f32x4* ldsW, f32x4* ldsM, int lane)
{
#pragma unroll
    for (int i = 0; i < 4; ++i) {
        __builtin_amdgcn_global_load_lds(
            (const GLOBAL_AS void*)&Wrow[c * 256 + i * 64 + lane],
            (LDS_AS void*)&ldsW[i * 64], 16, 0, 0);
        __builtin_amdgcn_global_load_lds(
            (const GLOBAL_AS void*)&Mrow[c * 256 + i * 64 + lane],
            (LDS_AS void*)&ldsM[i * 64], 16, 0, 0);
    }
}

template <bool FINAL>
__global__ __launch_bounds__(256) void snn_layer(
    const float* __restrict__ W, const float* __restrict__ Mk,
    const unsigned int* __restrict__ in_mask,   // 128 words = 4096 col bits
    unsigned char* __restrict__ out_mask,       // 512 bytes (if !FINAL)
    const int* __restrict__ t_steps, float* __restrict__ out)
{
    const int lane = threadIdx.x & 63;
    const int wave = threadIdx.x >> 6;
    const int row0 = blockIdx.x * 8 + wave * 2;         // block owns rows b*8..b*8+7
    const int row1 = row0 + 1;

    // 2 buffers x 4 KB per stream per wave: 64 KB/block -> 2 blocks/CU.
    __shared__ f32x4 sW[4][2][256];
    __shared__ f32x4 sM[4][2][256];
    __shared__ unsigned int smaskw[128];
    __shared__ int sbits[8];

    if (threadIdx.x < 128) smaskw[threadIdx.x] = in_mask[threadIdx.x];
    __syncthreads();                                    // drains mask load: vmcnt==0 after
    const unsigned char* smb = (const unsigned char*)smaskw;

    const f32x4* Wr0 = reinterpret_cast<const f32x4*>(W  + (size_t)row0 * N);
    const f32x4* Wr1 = reinterpret_cast<const f32x4*>(W  + (size_t)row1 * N);
    const f32x4* Mr0 = reinterpret_cast<const f32x4*>(Mk + (size_t)row0 * N);
    const f32x4* Mr1 = reinterpret_cast<const f32x4*>(Mk + (size_t)row1 * N);

    // Prologue: chunks 0,1 (row0) in flight -> 16 DMA ops outstanding.
    issue_chunk(Wr0, Mr0, 0, &sW[wave][0][0], &sM[wave][0][0], lane);
    issue_chunk(Wr0, Mr0, 1, &sW[wave][1][0], &sM[wave][1][0], lane);

    // 8 f64 chains: a* for row0, b* for row1 (exact: m in {0,1}, bit-masked).
    double a0 = 0, a1 = 0, a2 = 0, a3 = 0;
    double b0 = 0, b1 = 0, b2 = 0, b3 = 0;

    // Chunk K: rows0 for K<4, row1 for K>=4; column chunk c = K&3; buf = K&1.
#define STEP(K, WN)                                                            \
    do {                                                                       \
        asm volatile("s_waitcnt vmcnt(" WN ")" ::: "memory");                  \
        __builtin_amdgcn_sched_barrier(0);                                     \
        const int c = (K) & 3;                                                 \
        const f32x4* bw = &sW[wave][(K) & 1][0];                               \
        const f32x4* bm = &sM[wave][(K) & 1][0];                               \
        f32x4 w[4], m[4];                                                      \
        unsigned int nb[4];                                                    \
        _Pragma("unroll")                                                      \
        for (int i = 0; i < 4; ++i) {                                          \
            w[i] = bw[i * 64 + lane];                                          \
            m[i] = bm[i * 64 + lane];                                          \
            const int idx = c * 256 + i * 64 + lane;                           \
            nb[i] = ((unsigned int)smb[idx >> 1] >> ((idx & 1) * 4)) & 0xFu;   \
        }                                                                      \
        asm volatile("s_waitcnt lgkmcnt(0)" ::: "memory");                     \
        __builtin_amdgcn_sched_barrier(0);                                     \
        if ((K) + 2 < 8)                                                       \
            issue_chunk(((K) + 2 < 4) ? Wr0 : Wr1, ((K) + 2 < 4) ? Mr0 : Mr1,  \
                        ((K) + 2) & 3, &sW[wave][(K) & 1][0],                  \
                        &sM[wave][(K) & 1][0], lane);                          \
        double& r0 = ((K) < 4) ? a0 : b0;                                      \
        double& r1 = ((K) < 4) ? a1 : b1;                                      \
        double& r2 = ((K) < 4) ? a2 : b2;                                      \
        double& r3 = ((K) < 4) ? a3 : b3;                                      \
        _Pragma("unroll")                                                      \
        for (int i = 0; i < 4; ++i) {                                          \
            r0 = fma((double)w[i].x, (double)((nb[i] & 1u) ? m[i].x : 0.0f), r0); \
            r1 = fma((double)w[i].y, (double)((nb[i] & 2u) ? m[i].y : 0.0f), r1); \
            r2 = fma((double)w[i].z, (double)((nb[i] & 4u) ? m[i].z : 0.0f), r2); \
            r3 = fma((double)w[i].w, (double)((nb[i] & 8u) ? m[i].w : 0.0f), r3); \
        }                                                                      \
    } while (0)

    STEP(0, "8"); STEP(1, "8"); STEP(2, "8"); STEP(3, "8");
    STEP(4, "8"); STEP(5, "8"); STEP(6, "8"); STEP(7, "0");
#undef STEP

    double t0 = (a0 + a1) + (a2 + a3);
    double t1 = (b0 + b1) + (b2 + b3);
#pragma unroll
    for (int off = 32; off > 0; off >>= 1) {
        t0 += __shfl_down(t0, off, 64);
        t1 += __shfl_down(t1, off, 64);
    }

    if (FINAL) {
        if (lane == 0) {
            const float sc = 1.0f / (float)t_steps[0];
            out[row0] = (t0 > 1.0) ? sc : 0.0f;
            out[row1] = (t1 > 1.0) ? sc : 0.0f;
        }
    } else {
        if (lane == 0) {
            sbits[2 * wave]     = (t0 > 1.0) ? 1 : 0;
            sbits[2 * wave + 1] = (t1 > 1.0) ? 1 : 0;
        }
        __syncthreads();
        if (threadIdx.x == 0) {
            unsigned int byte = 0;
#pragma unroll
            for (int i = 0; i < 8; ++i) byte |= (unsigned int)sbits[i] << i;
            out_mask[blockIdx.x] = (unsigned char)byte;
        }
    }
}

extern "C" void kernel_launch(void* const* d_in, const int* in_sizes, int n_in,
                              void* d_out, int out_size, void* d_ws, size_t ws_size,
                              hipStream_t stream)
{
    const float* x  = (const float*)d_in[0];
    const float* u  = (const float*)d_in[1];
    const float* W0 = (const float*)d_in[2];
    const float* W1 = (const float*)d_in[3];
    const float* W2 = (const float*)d_in[4];
    const float* M0 = (const float*)d_in[5];
    const float* M1 = (const float*)d_in[6];
    const float* M2 = (const float*)d_in[7];
    const int* t_steps = (const int*)d_in[8];
    float* out = (float*)d_out;

    // Workspace: three 512 B bitmasks, each fully rewritten every call
    // before being read (re-poison safe, no memsets needed).
    unsigned long long* emask = (unsigned long long*)d_ws;          // 512 B
    unsigned char* m0 = (unsigned char*)d_ws + 512;                 // 512 B
    unsigned char* m1 = (unsigned char*)d_ws + 1024;                // 512 B

    enc_kernel<<<dim3(16), dim3(256), 0, stream>>>(x, u, emask);
    snn_layer<false><<<dim3(512), dim3(256), 0, stream>>>(
        W0, M0, (const unsigned int*)emask, m0, nullptr, nullptr);
    snn_layer<false><<<dim3(512), dim3(256), 0, stream>>>(
        W1, M1, (const unsigned int*)m0, m1, nullptr, nullptr);
    snn_layer<true><<<dim3(512), dim3(256), 0, stream>>>(
        W2, M2, (const unsigned int*)m1, nullptr, t_steps, out);
}